// Round 5
// baseline (3732.331 us; speedup 1.0000x reference)
//
#include <hip/hip_runtime.h>

// PositiveWaveFunction: 32-step tanh RNN, batch 8192, hidden 1024.
// R5: persistent fused kernel, low-pressure variant. Each of 256 blocks owns
// 32 batch rows; h lives in LDS ping-pong (128 KB); W_hh streamed from L2
// direct-to-registers each step. Per-step logits computed in the epilogue as
// per-wave partials -> global plog[31][8192][8][2]; separate finalize kernel
// (proven R1 pattern) does softmax + permutation weights.
// R4's spill-prone extras (augmented W, rotating owner wave, in-kernel
// softmax/stash) removed: target VGPR ~170 < 256 cap, no scratch.

typedef __bf16 bf16;
typedef __bf16 bf16x8 __attribute__((ext_vector_type(8)));
typedef float  f32x4  __attribute__((ext_vector_type(4)));

#define HID   1024
#define BATCH 8192
#define NSPIN 32

__device__ __forceinline__ float tanh_fast(float x) {
    float ax = fabsf(x);
    float t  = __expf(-2.0f * ax);                       // (0,1], no overflow
    float r  = (1.0f - t) * __builtin_amdgcn_rcpf(1.0f + t);
    return __builtin_copysignf(r, x);
}

// element-index swizzle for hb rows (2048B rows): XOR elem bits 3..5 with row bits 0..2
__device__ __forceinline__ int swz(int row, int elem) { return elem ^ ((row & 7) << 3); }

// ---------------- prep: W cast, u0/u1, packed bit-words, factorials ----------------

__global__ void prep(const float* __restrict__ din, const float* __restrict__ Wih,
                     const float* __restrict__ Whh, const float* __restrict__ bih,
                     const float* __restrict__ bhh,
                     bf16* __restrict__ Wp, float* __restrict__ u0, float* __restrict__ u1,
                     unsigned int* __restrict__ words, float* __restrict__ fact) {
    long idx = (long)blockIdx.x * blockDim.x + threadIdx.x;
    long stride = (long)gridDim.x * blockDim.x;
    for (long i = idx; i < (long)HID * HID; i += stride) Wp[i] = (bf16)Whh[i];
    for (long i = idx; i < HID; i += stride) {
        u0[i] = Wih[i * 2 + 0] + bih[i] + bhh[i];
        u1[i] = Wih[i * 2 + 1] + bih[i] + bhh[i];
    }
    for (long b = idx; b < BATCH; b += stride) {
        unsigned int wv = 0;
        for (int j = 0; j < 31; ++j)
            wv |= (din[((long)j * BATCH + b) * 2 + 1] != 0.0f ? 1u : 0u) << j;
        words[b] = wv;
    }
    if (idx == 0) {  // factorials: float64 cumprod cast to float32, like reference
        double f = 1.0; fact[0] = 1.0f;
        for (int k = 1; k <= NSPIN; ++k) { f *= k; fact[k] = (float)f; }
    }
}

// single block: logits of h[0] = tanh(u0) (identical for all batch rows)
__global__ void prep2(const float* __restrict__ u0, const float* __restrict__ Wlin,
                      const float* __restrict__ blin, float* __restrict__ l0s) {
    __shared__ float red0[16], red1[16];
    int t = threadIdx.x;  // 0..1023
    float hv = tanh_fast(u0[t]);
    float s0 = hv * Wlin[t], s1 = hv * Wlin[HID + t];
    #pragma unroll
    for (int off = 1; off < 64; off <<= 1) {
        s0 += __shfl_xor(s0, off, 64);
        s1 += __shfl_xor(s1, off, 64);
    }
    if ((t & 63) == 0) { red0[t >> 6] = s0; red1[t >> 6] = s1; }
    __syncthreads();
    if (t == 0) {
        float a = blin[0], b = blin[1];
        for (int i = 0; i < 16; ++i) { a += red0[i]; b += red1[i]; }
        l0s[0] = a; l0s[1] = b;
    }
}

// ---------------- persistent fused RNN ----------------
// 256 blocks x 512 threads (8 waves). Block owns rows [32*blk, 32*blk+32).
// Wave w computes output cols [128w, 128w+128) as 2x8 16x16 frags, K=1024.
// Epilogue: tanh -> hb[pout] + per-wave logit partials -> plog (global).

__global__ __launch_bounds__(512, 2) void rnn_fused(
        const bf16* __restrict__ Wp, const float* __restrict__ u0g,
        const float* __restrict__ u1g, const unsigned int* __restrict__ words,
        const float* __restrict__ Wlin, float* __restrict__ plog) {
    __shared__ __align__(16) bf16 hb[2][32][1024];   // 128 KB ping-pong h (swizzled)
    __shared__ float lu[2][1024];                     // u0/u1, 8 KB
    __shared__ float lw[2][1024];                     // W_lin rows, 8 KB

    const int tid = threadIdx.x;
    const int w = tid >> 6, l = tid & 63;
    const int fr = l & 15, fq = l >> 4;
    const int rowbase = blockIdx.x * 32;

    for (int i = tid; i < HID; i += 512) {
        lu[0][i] = u0g[i]; lu[1][i] = u1g[i];
        lw[0][i] = Wlin[i]; lw[1][i] = Wlin[HID + i];
    }

    // h[0] = tanh(u0), identical for all rows
    {
        int k0 = tid * 2;
        bf16 b0 = (bf16)tanh_fast(u0g[k0]);
        bf16 b1 = (bf16)tanh_fast(u0g[k0 + 1]);
        #pragma unroll 4
        for (int r = 0; r < 32; ++r) {
            int sw = (r & 7) << 3;
            hb[0][r][k0 ^ sw] = b0;
            hb[0][r][(k0 + 1) ^ sw] = b1;
        }
    }

    // per-lane resident: packed bit-words for the 8 epilogue rows
    unsigned int wrd[2][4];
    #pragma unroll
    for (int rf = 0; rf < 2; ++rf)
        #pragma unroll
        for (int rr = 0; rr < 4; ++rr)
            wrd[rf][rr] = words[rowbase + rf * 16 + fq * 4 + rr];

    const bf16* gW = Wp + ((long)(w * 128 + fr)) * HID + fq * 8;

    __syncthreads();

    for (int s = 1; s <= 31; ++s) {
        const int pin = (s - 1) & 1, pout = s & 1;
        f32x4 acc[2][8] = {};

        #pragma unroll
        for (int kt = 0; kt < 16; ++kt) {
            bf16x8 af[2][2];
            #pragma unroll
            for (int rf = 0; rf < 2; ++rf)
                #pragma unroll
                for (int kk = 0; kk < 2; ++kk) {
                    const int row = rf * 16 + fr;
                    af[rf][kk] = *(const bf16x8*)&hb[pin][row][swz(row, kt * 64 + kk * 32 + fq * 8)];
                }
            bf16x8 wt[8][2];
            #pragma unroll
            for (int cf = 0; cf < 8; ++cf)
                #pragma unroll
                for (int kk = 0; kk < 2; ++kk)
                    wt[cf][kk] = *(const bf16x8*)(gW + (long)cf * 16 * HID + kt * 64 + kk * 32);
            #pragma unroll
            for (int rf = 0; rf < 2; ++rf)
                #pragma unroll
                for (int cf = 0; cf < 8; ++cf)
                    #pragma unroll
                    for (int kk = 0; kk < 2; ++kk)
                        acc[rf][cf] = __builtin_amdgcn_mfma_f32_16x16x32_bf16(
                            af[rf][kk], wt[cf][kk], acc[rf][cf], 0, 0, 0);
        }

        __syncthreads();   // all hb[pin] reads done before any epilogue LDS write

        // epilogue: z + u_bit -> tanh -> hb[pout]; per-wave logit partials -> plog
        #pragma unroll
        for (int rf = 0; rf < 2; ++rf)
            #pragma unroll
            for (int rr = 0; rr < 4; ++rr) {
                const int row = rf * 16 + fq * 4 + rr;
                const int bt = (wrd[rf][rr] >> (s - 1)) & 1;
                float s0 = 0.f, s1 = 0.f;
                #pragma unroll
                for (int cf = 0; cf < 8; ++cf) {
                    const int col = w * 128 + cf * 16 + fr;
                    const float hv = tanh_fast(acc[rf][cf][rr] + lu[bt][col]);
                    hb[pout][row][swz(row, col)] = (bf16)hv;
                    s0 += hv * lw[0][col];
                    s1 += hv * lw[1][col];
                }
                #pragma unroll
                for (int off = 1; off < 16; off <<= 1) {
                    s0 += __shfl_xor(s0, off, 16);
                    s1 += __shfl_xor(s1, off, 16);
                }
                if (fr == 0) {
                    const long rowg = rowbase + row;
                    *(float2*)&plog[(((long)(s - 1) * BATCH + rowg)) * 16 + w * 2] =
                        make_float2(s0, s1);
                }
            }
        __syncthreads();
    }
}

// ---------------- finalize: softmax + permutation weights ----------------

__global__ void finalize(const float* __restrict__ plog, const float* __restrict__ l0s,
                         const float* __restrict__ blin, const unsigned int* __restrict__ words,
                         const float* __restrict__ fact, float* __restrict__ out) {
    long idx = (long)blockIdx.x * blockDim.x + threadIdx.x;
    if (idx >= (long)NSPIN * BATCH) return;
    int s = (int)(idx / BATCH), b = (int)(idx % BATCH);

    float l0, l1;
    if (s == 0) { l0 = l0s[0]; l1 = l0s[1]; }
    else {
        l0 = blin[0]; l1 = blin[1];
        const float* ps = plog + ((long)(s - 1) * BATCH + b) * 16;
        #pragma unroll
        for (int k = 0; k < 8; ++k) {
            l0 += ps[k * 2 + 0];
            l1 += ps[k * 2 + 1];
        }
    }
    float mx = fmaxf(l0, l1);
    float e0 = __expf(l0 - mx), e1 = __expf(l1 - mx);
    float p0 = e0 / (e0 + e1), p1 = e1 / (e0 + e1);
    if (s > 0) {
        const unsigned int wv = words[b];
        const int cd = __popc(wv & ((1u << s) - 1));
        const float cdf = (float)cd, cuf = (float)(s - cd);
        const float ku = 16.f - cuf, kd = 16.f - cdf;
        const int n = NSPIN - s;
        const int kui = (int)fminf(fmaxf(ku, 0.f), 32.f);
        const int kdi = (int)fminf(fmaxf(kd, 0.f), 32.f);
        const float wu = fact[n] / fact[kui] * (ku >= 0.f ? 1.f : 0.f) + 1e-12f;
        const float wd = fact[n] / fact[kdi] * (kd >= 0.f ? 1.f : 0.f) + 1e-12f;
        p0 *= wu; p1 *= wd;
    }
    float inv = 1.f / (p0 + p1);
    out[idx * 2 + 0] = p0 * inv;
    out[idx * 2 + 1] = p1 * inv;
}

// ---------------- launch ----------------

extern "C" void kernel_launch(void* const* d_in, const int* in_sizes, int n_in,
                              void* d_out, int out_size, void* d_ws, size_t ws_size,
                              hipStream_t stream) {
    const float* din  = (const float*)d_in[0];  // [32][8192][2]
    const float* Wih  = (const float*)d_in[1];  // [1024][2]
    const float* Whh  = (const float*)d_in[2];  // [1024][1024]
    const float* bih  = (const float*)d_in[3];  // [1024]
    const float* bhh  = (const float*)d_in[4];  // [1024]
    const float* Wlin = (const float*)d_in[5];  // [2][1024]
    const float* blin = (const float*)d_in[6];  // [2]
    float* out = (float*)d_out;

    char* ws = (char*)d_ws;
    size_t o = 0;
    auto alloc = [&](size_t b) { size_t r = o; o += (b + 255) & ~(size_t)255; return r; };
    bf16*  Wp   = (bf16*)(ws + alloc((size_t)HID * HID * 2));
    float* u0   = (float*)(ws + alloc(HID * 4));
    float* u1   = (float*)(ws + alloc(HID * 4));
    float* l0s  = (float*)(ws + alloc(2 * 4));
    float* fact = (float*)(ws + alloc(33 * 4));
    unsigned int* words = (unsigned int*)(ws + alloc((size_t)BATCH * 4));
    float* plog = (float*)(ws + alloc(31L * BATCH * 8 * 2 * 4));

    prep<<<512, 256, 0, stream>>>(din, Wih, Whh, bih, bhh, Wp, u0, u1, words, fact);
    prep2<<<1, 1024, 0, stream>>>(u0, Wlin, blin, l0s);
    rnn_fused<<<256, 512, 0, stream>>>(Wp, u0, u1, words, Wlin, plog);
    finalize<<<(NSPIN * BATCH) / 256, 256, 0, stream>>>(plog, l0s, blin, words, fact, out);
}

// Round 6
// 837.244 us; speedup vs baseline: 4.4579x; 4.4579x over previous
//
#include <hip/hip_runtime.h>

// PositiveWaveFunction: 32-step tanh RNN, batch 8192, hidden 1024.
// R6: back to R1's per-step GEMM skeleton (proven 992 us) with:
//  - static-index double-buffered LDS (4 distinct __shared__ arrays, macro
//    bodies; rule #20) so prefetch of tile k+1 is in flight over compute of k
//  - XOR bank-swizzle via pre-permuted global_load_lds SOURCE addresses +
//    XOR'd ds_read (rule #21): kills the 16-way conflict of 128B-stride rows
//  - 128x256 tiles, grid (64,4), 8 waves; halves h re-read traffic vs 128x128
// Epilogue fuses bias-select + tanh + bf16 h-store + per-wave logit partials
// (16 slots); finalize does softmax + permutation weights.

typedef __bf16 bf16;
typedef __bf16 bf16x8 __attribute__((ext_vector_type(8)));
typedef float  f32x4  __attribute__((ext_vector_type(4)));

#define HID   1024
#define BATCH 8192
#define NSPIN 32

__device__ __forceinline__ float tanh_fast(float x) {
    float ax = fabsf(x);
    float t  = __expf(-2.0f * ax);                       // (0,1], no overflow
    float r  = (1.0f - t) * __builtin_amdgcn_rcpf(1.0f + t);
    return __builtin_copysignf(r, x);
}

// ---------------- prep kernels ----------------

__global__ void prep1(const float* __restrict__ din, const float* __restrict__ Wih,
                      const float* __restrict__ Whh, const float* __restrict__ bih,
                      const float* __restrict__ bhh,
                      bf16* __restrict__ Wbf, float* __restrict__ u0, float* __restrict__ u1,
                      unsigned char* __restrict__ bits, unsigned int* __restrict__ words,
                      float* __restrict__ fact) {
    long idx = (long)blockIdx.x * blockDim.x + threadIdx.x;
    long stride = (long)gridDim.x * blockDim.x;
    for (long i = idx; i < (long)HID * HID; i += stride) Wbf[i] = (bf16)Whh[i];
    for (long i = idx; i < HID; i += stride) {
        u0[i] = Wih[i * 2 + 0] + bih[i] + bhh[i];
        u1[i] = Wih[i * 2 + 1] + bih[i] + bhh[i];
    }
    for (long i = idx; i < 31L * BATCH; i += stride) {
        long j = i / BATCH, b = i % BATCH;
        bits[i] = (unsigned char)(din[(j * BATCH + b) * 2 + 1] != 0.0f);
    }
    for (long b = idx; b < BATCH; b += stride) {
        unsigned int wv = 0;
        for (int j = 0; j < 31; ++j)
            wv |= (din[((long)j * BATCH + b) * 2 + 1] != 0.0f ? 1u : 0u) << j;
        words[b] = wv;
    }
    if (idx == 0) {  // factorials: float64 cumprod cast to float32, like reference
        double f = 1.0; fact[0] = 1.0f;
        for (int k = 1; k <= NSPIN; ++k) { f *= k; fact[k] = (float)f; }
    }
}

// single block: h after step 0 (identical for all batch rows) + its logits
__global__ void prep2(const float* __restrict__ u0, const float* __restrict__ Wlin,
                      const float* __restrict__ blin,
                      bf16* __restrict__ hrow, float* __restrict__ l0s) {
    __shared__ float red0[16], red1[16];
    int t = threadIdx.x;  // 0..1023
    float hv = tanh_fast(u0[t]);
    hrow[t] = (bf16)hv;
    float s0 = hv * Wlin[t], s1 = hv * Wlin[HID + t];
    #pragma unroll
    for (int off = 1; off < 64; off <<= 1) {
        s0 += __shfl_xor(s0, off, 64);
        s1 += __shfl_xor(s1, off, 64);
    }
    if ((t & 63) == 0) { red0[t >> 6] = s0; red1[t >> 6] = s1; }
    __syncthreads();
    if (t == 0) {
        float a = blin[0], b = blin[1];
        for (int i = 0; i < 16; ++i) { a += red0[i]; b += red1[i]; }
        l0s[0] = a; l0s[1] = b;
    }
}

// broadcast hrow to all 8192 rows of the ping buffer
__global__ void fillh(const bf16* __restrict__ hrow, bf16* __restrict__ hping) {
    const bf16x8* src = (const bf16x8*)hrow;   // 128 vectors per row
    bf16x8* dst = (bf16x8*)hping;
    long n8 = (long)BATCH * HID / 8;
    for (long v = (long)blockIdx.x * blockDim.x + threadIdx.x; v < n8;
         v += (long)gridDim.x * blockDim.x)
        dst[v] = src[v & 127];
}

// ---------------- main recurrence GEMM ----------------
// Z = h_in @ W_hh^T ; z += (bit ? u1 : u0) ; h_out = tanh(z) (bf16)
// partial logits per wave-column -> plog[31][8192][16][2]
// Tile 128x256, BK=64, 8 waves (2x4 of 64x64), 16x16x32 bf16 MFMA.
// LDS tiles [row][64] with 16B-chunk XOR swizzle: LDS[r][slot] holds global
// chunk (slot ^ (r&7)); staging permutes the GLOBAL source (per-lane addr),
// ds_read applies the same XOR -> 2-way banks (free).

__global__ __launch_bounds__(512, 2) void gemm_step(
        const bf16* __restrict__ hin, bf16* __restrict__ hout,
        const bf16* __restrict__ Wbf,
        const float* __restrict__ u0, const float* __restrict__ u1,
        const unsigned char* __restrict__ bits_s,
        const float* __restrict__ Wlin,
        float* __restrict__ plog_s) {
    __shared__ __align__(16) bf16 sA0[128 * 64];
    __shared__ __align__(16) bf16 sA1[128 * 64];
    __shared__ __align__(16) bf16 sB0[256 * 64];
    __shared__ __align__(16) bf16 sB1[256 * 64];

    const int tid = threadIdx.x;
    const int w = tid >> 6, l = tid & 63;
    const long rowM = (long)blockIdx.x * 128;
    const int  colN = blockIdx.y * 256;

    const int wr = w >> 2, wc = w & 3;      // 2x4 wave grid (64x64 tiles)
    const int fr = l & 15, fq = l >> 4;     // fragment lane coords

    f32x4 acc[4][4] = {};

    // staging row/chunk decomposition (per lane): 8 rows x 8 chunks per issue
    const int lrow = l >> 3;                 // 0..7
    const int lchk = l & 7;                  // 0..7 (16B chunk)

#define STAGE(SA, SB, kt_) do {                                                              \
    const int kbase_ = (kt_) * 64;                                                           \
    _Pragma("unroll")                                                                        \
    for (int i = 0; i < 2; ++i) {                                                            \
        const int r_ = w * 16 + i * 8 + lrow;                                                \
        const int sc_ = (lchk ^ (r_ & 7)) * 8;                                               \
        __builtin_amdgcn_global_load_lds(                                                    \
            (const __attribute__((address_space(1))) void*)(hin + (rowM + r_) * HID + kbase_ + sc_), \
            (__attribute__((address_space(3))) void*)(&SA[(w * 16 + i * 8) * 64]), 16, 0, 0); \
    }                                                                                        \
    _Pragma("unroll")                                                                        \
    for (int i = 0; i < 4; ++i) {                                                            \
        const int r_ = w * 32 + i * 8 + lrow;                                                \
        const int sc_ = (lchk ^ (r_ & 7)) * 8;                                               \
        __builtin_amdgcn_global_load_lds(                                                    \
            (const __attribute__((address_space(1))) void*)(Wbf + (long)(colN + r_) * HID + kbase_ + sc_), \
            (__attribute__((address_space(3))) void*)(&SB[(w * 32 + i * 8) * 64]), 16, 0, 0); \
    }                                                                                        \
} while (0)

#define COMPUTE(SA, SB) do {                                                                 \
    _Pragma("unroll")                                                                        \
    for (int kk = 0; kk < 2; ++kk) {                                                         \
        bf16x8 af[4], bfr[4];                                                                \
        _Pragma("unroll")                                                                    \
        for (int m = 0; m < 4; ++m) {                                                        \
            const int ra_ = wr * 64 + m * 16 + fr;                                           \
            af[m] = *(const bf16x8*)&SA[ra_ * 64 + ((kk * 32 + fq * 8) ^ ((ra_ & 7) << 3))]; \
        }                                                                                    \
        _Pragma("unroll")                                                                    \
        for (int n = 0; n < 4; ++n) {                                                        \
            const int rb_ = wc * 64 + n * 16 + fr;                                           \
            bfr[n] = *(const bf16x8*)&SB[rb_ * 64 + ((kk * 32 + fq * 8) ^ ((rb_ & 7) << 3))];\
        }                                                                                    \
        _Pragma("unroll")                                                                    \
        for (int m = 0; m < 4; ++m)                                                          \
            _Pragma("unroll")                                                                \
            for (int n = 0; n < 4; ++n)                                                      \
                acc[m][n] = __builtin_amdgcn_mfma_f32_16x16x32_bf16(af[m], bfr[n], acc[m][n], 0, 0, 0); \
    }                                                                                        \
} while (0)

    STAGE(sA0, sB0, 0);
    __syncthreads();                       // buf0 ready

    for (int kt2 = 0; kt2 < 8; ++kt2) {
        STAGE(sA1, sB1, 2 * kt2 + 1);      // prefetch odd tile over compute(even)
        COMPUTE(sA0, sB0);
        __syncthreads();                   // drain lands after MFMA cover
        if (kt2 < 7) STAGE(sA0, sB0, 2 * kt2 + 2);  // prefetch even over compute(odd)
        COMPUTE(sA1, sB1);
        __syncthreads();
    }
#undef STAGE
#undef COMPUTE

    // epilogue: bias-select + tanh + bf16 store + partial logits
    float u0v[4], u1v[4], wl0[4], wl1[4];
    int colg[4];
    #pragma unroll
    for (int n = 0; n < 4; ++n) {
        int c = colN + wc * 64 + n * 16 + fr;
        colg[n] = c;
        u0v[n] = u0[c]; u1v[n] = u1[c];
        wl0[n] = Wlin[c]; wl1[n] = Wlin[HID + c];
    }
    const int slot = blockIdx.y * 4 + wc;   // 16 slots

    #pragma unroll
    for (int m = 0; m < 4; ++m) {
        #pragma unroll
        for (int r = 0; r < 4; ++r) {
            long rowg = rowM + wr * 64 + m * 16 + fq * 4 + r;
            int bt = bits_s[rowg];
            float s0 = 0.f, s1 = 0.f;
            #pragma unroll
            for (int n = 0; n < 4; ++n) {
                float z  = acc[m][n][r] + (bt ? u1v[n] : u0v[n]);
                float hv = tanh_fast(z);
                hout[rowg * HID + colg[n]] = (bf16)hv;
                s0 += hv * wl0[n];
                s1 += hv * wl1[n];
            }
            #pragma unroll
            for (int off = 1; off < 16; off <<= 1) {
                s0 += __shfl_xor(s0, off, 16);
                s1 += __shfl_xor(s1, off, 16);
            }
            if (fr == 0)
                *(float2*)&plog_s[rowg * 32 + slot * 2] = make_float2(s0, s1);
        }
    }
}

// ---------------- finalize: softmax + permutation weights ----------------

__global__ void finalize(const float* __restrict__ plog, const float* __restrict__ l0s,
                         const float* __restrict__ blin, const unsigned int* __restrict__ words,
                         const float* __restrict__ fact, float* __restrict__ out) {
    long idx = (long)blockIdx.x * blockDim.x + threadIdx.x;
    if (idx >= (long)NSPIN * BATCH) return;
    int s = (int)(idx / BATCH), b = (int)(idx % BATCH);

    float l0, l1;
    if (s == 0) { l0 = l0s[0]; l1 = l0s[1]; }
    else {
        l0 = blin[0]; l1 = blin[1];
        const float* ps = plog + ((long)(s - 1) * BATCH + b) * 32;
        #pragma unroll
        for (int k = 0; k < 16; ++k) {
            l0 += ps[k * 2 + 0];
            l1 += ps[k * 2 + 1];
        }
    }
    float mx = fmaxf(l0, l1);
    float e0 = __expf(l0 - mx), e1 = __expf(l1 - mx);
    float p0 = e0 / (e0 + e1), p1 = e1 / (e0 + e1);
    if (s > 0) {
        const unsigned int wv = words[b];
        const int cd = __popc(wv & ((1u << s) - 1));
        const float cdf = (float)cd, cuf = (float)(s - cd);
        const float ku = 16.f - cuf, kd = 16.f - cdf;
        const int n = NSPIN - s;
        const int kui = (int)fminf(fmaxf(ku, 0.f), 32.f);
        const int kdi = (int)fminf(fmaxf(kd, 0.f), 32.f);
        const float wu = fact[n] / fact[kui] * (ku >= 0.f ? 1.f : 0.f) + 1e-12f;
        const float wd = fact[n] / fact[kdi] * (kd >= 0.f ? 1.f : 0.f) + 1e-12f;
        p0 *= wu; p1 *= wd;
    }
    float inv = 1.f / (p0 + p1);
    out[idx * 2 + 0] = p0 * inv;
    out[idx * 2 + 1] = p1 * inv;
}

// ---------------- launch ----------------

extern "C" void kernel_launch(void* const* d_in, const int* in_sizes, int n_in,
                              void* d_out, int out_size, void* d_ws, size_t ws_size,
                              hipStream_t stream) {
    const float* din  = (const float*)d_in[0];  // [32][8192][2]
    const float* Wih  = (const float*)d_in[1];  // [1024][2]
    const float* Whh  = (const float*)d_in[2];  // [1024][1024]
    const float* bih  = (const float*)d_in[3];  // [1024]
    const float* bhh  = (const float*)d_in[4];  // [1024]
    const float* Wlin = (const float*)d_in[5];  // [2][1024]
    const float* blin = (const float*)d_in[6];  // [2]
    float* out = (float*)d_out;

    char* ws = (char*)d_ws;
    size_t o = 0;
    auto alloc = [&](size_t b) { size_t r = o; o += (b + 255) & ~(size_t)255; return r; };
    bf16*  Wbf  = (bf16*)(ws + alloc((size_t)HID * HID * 2));
    float* u0   = (float*)(ws + alloc(HID * 4));
    float* u1   = (float*)(ws + alloc(HID * 4));
    bf16*  hrow = (bf16*)(ws + alloc(HID * 2));
    float* l0s  = (float*)(ws + alloc(2 * 4));
    float* fact = (float*)(ws + alloc(33 * 4));
    unsigned char* bits = (unsigned char*)(ws + alloc(31L * BATCH));
    unsigned int* words = (unsigned int*)(ws + alloc((size_t)BATCH * 4));
    bf16*  hA   = (bf16*)(ws + alloc((size_t)BATCH * HID * 2));
    bf16*  hB   = (bf16*)(ws + alloc((size_t)BATCH * HID * 2));
    float* plog = (float*)(ws + alloc(31L * BATCH * 16 * 2 * 4));

    prep1<<<1024, 256, 0, stream>>>(din, Wih, Whh, bih, bhh, Wbf, u0, u1, bits, words, fact);
    prep2<<<1, 1024, 0, stream>>>(u0, Wlin, blin, hrow, l0s);
    fillh<<<2048, 256, 0, stream>>>(hrow, hA);

    bf16* hin = hA; bf16* hout = hB;
    for (int s = 1; s <= 31; ++s) {
        gemm_step<<<dim3(64, 4), 512, 0, stream>>>(
            hin, hout, Wbf, u0, u1,
            bits + (size_t)(s - 1) * BATCH, Wlin,
            plog + (size_t)(s - 1) * BATCH * 32);
        bf16* t = hin; hin = hout; hout = t;
    }
    finalize<<<(NSPIN * BATCH) / 256, 256, 0, stream>>>(plog, l0s, blin, words, fact, out);
}

// Round 7
// 763.079 us; speedup vs baseline: 4.8911x; 1.0972x over previous
//
#include <hip/hip_runtime.h>

// PositiveWaveFunction: 32-step tanh RNN, batch 8192, hidden 1024.
// R7: R6 skeleton (128x256 tile, 8 waves, BK=64, swizzled global_load_lds)
// with a depth-3 counted-vmcnt pipeline (T3+T4): 3 LDS buffers, tiles t+1 and
// t+2 in flight during compute of t; tile boundary = sched_barrier +
// s_waitcnt vmcnt(6) + raw s_barrier (never a full drain mid-loop); setprio
// around MFMA clusters (T5). Epilogue VMEM loads pinned after the K-loop so
// in-loop vmcnt counting stays exact.

typedef __bf16 bf16;
typedef __bf16 bf16x8 __attribute__((ext_vector_type(8)));
typedef float  f32x4  __attribute__((ext_vector_type(4)));

#define HID   1024
#define BATCH 8192
#define NSPIN 32

#define AS1 __attribute__((address_space(1)))
#define AS3 __attribute__((address_space(3)))

__device__ __forceinline__ float tanh_fast(float x) {
    float ax = fabsf(x);
    float t  = __expf(-2.0f * ax);                       // (0,1], no overflow
    float r  = (1.0f - t) * __builtin_amdgcn_rcpf(1.0f + t);
    return __builtin_copysignf(r, x);
}

// ---------------- prep kernels ----------------

__global__ void prep1(const float* __restrict__ din, const float* __restrict__ Wih,
                      const float* __restrict__ Whh, const float* __restrict__ bih,
                      const float* __restrict__ bhh,
                      bf16* __restrict__ Wbf, float* __restrict__ u0, float* __restrict__ u1,
                      unsigned char* __restrict__ bits, unsigned int* __restrict__ words,
                      float* __restrict__ fact) {
    long idx = (long)blockIdx.x * blockDim.x + threadIdx.x;
    long stride = (long)gridDim.x * blockDim.x;
    for (long i = idx; i < (long)HID * HID; i += stride) Wbf[i] = (bf16)Whh[i];
    for (long i = idx; i < HID; i += stride) {
        u0[i] = Wih[i * 2 + 0] + bih[i] + bhh[i];
        u1[i] = Wih[i * 2 + 1] + bih[i] + bhh[i];
    }
    for (long i = idx; i < 31L * BATCH; i += stride) {
        long j = i / BATCH, b = i % BATCH;
        bits[i] = (unsigned char)(din[(j * BATCH + b) * 2 + 1] != 0.0f);
    }
    for (long b = idx; b < BATCH; b += stride) {
        unsigned int wv = 0;
        for (int j = 0; j < 31; ++j)
            wv |= (din[((long)j * BATCH + b) * 2 + 1] != 0.0f ? 1u : 0u) << j;
        words[b] = wv;
    }
    if (idx == 0) {  // factorials: float64 cumprod cast to float32, like reference
        double f = 1.0; fact[0] = 1.0f;
        for (int k = 1; k <= NSPIN; ++k) { f *= k; fact[k] = (float)f; }
    }
}

// single block: h after step 0 (identical for all batch rows) + its logits
__global__ void prep2(const float* __restrict__ u0, const float* __restrict__ Wlin,
                      const float* __restrict__ blin,
                      bf16* __restrict__ hrow, float* __restrict__ l0s) {
    __shared__ float red0[16], red1[16];
    int t = threadIdx.x;  // 0..1023
    float hv = tanh_fast(u0[t]);
    hrow[t] = (bf16)hv;
    float s0 = hv * Wlin[t], s1 = hv * Wlin[HID + t];
    #pragma unroll
    for (int off = 1; off < 64; off <<= 1) {
        s0 += __shfl_xor(s0, off, 64);
        s1 += __shfl_xor(s1, off, 64);
    }
    if ((t & 63) == 0) { red0[t >> 6] = s0; red1[t >> 6] = s1; }
    __syncthreads();
    if (t == 0) {
        float a = blin[0], b = blin[1];
        for (int i = 0; i < 16; ++i) { a += red0[i]; b += red1[i]; }
        l0s[0] = a; l0s[1] = b;
    }
}

// broadcast hrow to all 8192 rows of the ping buffer
__global__ void fillh(const bf16* __restrict__ hrow, bf16* __restrict__ hping) {
    const bf16x8* src = (const bf16x8*)hrow;   // 128 vectors per row
    bf16x8* dst = (bf16x8*)hping;
    long n8 = (long)BATCH * HID / 8;
    for (long v = (long)blockIdx.x * blockDim.x + threadIdx.x; v < n8;
         v += (long)gridDim.x * blockDim.x)
        dst[v] = src[v & 127];
}

// ---------------- main recurrence GEMM ----------------
// Z = h_in @ W_hh^T ; z += (bit ? u1 : u0) ; h_out = tanh(z) (bf16)
// partial logits per wave-column -> plog[31][8192][16][2]
// Tile 128x256, BK=64, 8 waves (2x4 of 64x64), 16x16x32 bf16 MFMA.
// 3-buffer LDS pipeline, counted vmcnt(6) at tile boundaries.

__global__ __launch_bounds__(512, 2) void gemm_step(
        const bf16* __restrict__ hin, bf16* __restrict__ hout,
        const bf16* __restrict__ Wbf,
        const float* __restrict__ u0, const float* __restrict__ u1,
        const unsigned char* __restrict__ bits_s,
        const float* __restrict__ Wlin,
        float* __restrict__ plog_s) {
    __shared__ __align__(16) bf16 sA0[128 * 64];
    __shared__ __align__(16) bf16 sA1[128 * 64];
    __shared__ __align__(16) bf16 sA2[128 * 64];
    __shared__ __align__(16) bf16 sB0[256 * 64];
    __shared__ __align__(16) bf16 sB1[256 * 64];
    __shared__ __align__(16) bf16 sB2[256 * 64];

    const int tid = threadIdx.x;
    const int w = tid >> 6, l = tid & 63;
    const long rowM = (long)blockIdx.x * 128;
    const int  colN = blockIdx.y * 256;

    const int wr = w >> 2, wc = w & 3;      // 2x4 wave grid (64x64 tiles)
    const int fr = l & 15, fq = l >> 4;     // fragment lane coords

    f32x4 acc[4][4] = {};

    // staging row/chunk decomposition (per lane): 8 rows x 8 chunks per issue
    const int lrow = l >> 3;                 // 0..7
    const int lchk = l & 7;                  // 0..7 (16B chunk)

// stage A-half-tile rows (2 loads) / B rows pair (2 loads), 16B chunks,
// source pre-permuted so linear LDS dest == XOR-swizzled layout
#define STG_A(SA, KT) do {                                                                   \
    _Pragma("unroll")                                                                        \
    for (int i = 0; i < 2; ++i) {                                                            \
        const int r_ = w * 16 + i * 8 + lrow;                                                \
        const int sc_ = (lchk ^ (r_ & 7)) * 8;                                               \
        __builtin_amdgcn_global_load_lds(                                                    \
            (const AS1 void*)(hin + (rowM + r_) * HID + (KT) * 64 + sc_),                    \
            (AS3 void*)(&SA[(w * 16 + i * 8) * 64]), 16, 0, 0);                              \
    }                                                                                        \
} while (0)

#define STG_B2(SB, KT, I0) do {                                                              \
    _Pragma("unroll")                                                                        \
    for (int i = (I0); i < (I0) + 2; ++i) {                                                  \
        const int r_ = w * 32 + i * 8 + lrow;                                                \
        const int sc_ = (lchk ^ (r_ & 7)) * 8;                                               \
        __builtin_amdgcn_global_load_lds(                                                    \
            (const AS1 void*)(Wbf + (long)(colN + r_) * HID + (KT) * 64 + sc_),              \
            (AS3 void*)(&SB[(w * 32 + i * 8) * 64]), 16, 0, 0);                              \
    }                                                                                        \
} while (0)

#define RD_FRAGS(AF, BF, SA, SB, KK) do {                                                    \
    _Pragma("unroll")                                                                        \
    for (int m = 0; m < 4; ++m) {                                                            \
        const int ra_ = wr * 64 + m * 16 + fr;                                               \
        AF[m] = *(const bf16x8*)&SA[ra_ * 64 + (((KK) * 32 + fq * 8) ^ ((ra_ & 7) << 3))];   \
    }                                                                                        \
    _Pragma("unroll")                                                                        \
    for (int n = 0; n < 4; ++n) {                                                            \
        const int rb_ = wc * 64 + n * 16 + fr;                                               \
        BF[n] = *(const bf16x8*)&SB[rb_ * 64 + (((KK) * 32 + fq * 8) ^ ((rb_ & 7) << 3))];   \
    }                                                                                        \
} while (0)

#define MFMA16(AF, BF) do {                                                                  \
    __builtin_amdgcn_s_setprio(1);                                                           \
    _Pragma("unroll")                                                                        \
    for (int m = 0; m < 4; ++m)                                                              \
        _Pragma("unroll")                                                                    \
        for (int n = 0; n < 4; ++n)                                                          \
            acc[m][n] = __builtin_amdgcn_mfma_f32_16x16x32_bf16(AF[m], BF[n], acc[m][n], 0, 0, 0); \
    __builtin_amdgcn_s_setprio(0);                                                           \
} while (0)

// one K-tile: compute from (CA,CB); stage tile T+2 into (NA,NB) when T<=13;
// boundary: counted vmcnt (tile T+1 landed; T+2 still in flight) + raw barrier
#define BODY(CA, CB, NA, NB, T) do {                                                         \
    bf16x8 afx[4], bfx[4], afy[4], bfy[4];                                                   \
    RD_FRAGS(afx, bfx, CA, CB, 0);                                                           \
    if ((T) <= 13) { STG_A(NA, (T) + 2); STG_B2(NB, (T) + 2, 0); }                           \
    MFMA16(afx, bfx);                                                                        \
    RD_FRAGS(afy, bfy, CA, CB, 1);                                                           \
    if ((T) <= 13) { STG_B2(NB, (T) + 2, 2); }                                               \
    MFMA16(afy, bfy);                                                                        \
    __builtin_amdgcn_sched_barrier(0);                                                       \
    if ((T) <= 13)       asm volatile("s_waitcnt vmcnt(6)" ::: "memory");                    \
    else if ((T) == 14)  asm volatile("s_waitcnt vmcnt(0)" ::: "memory");                    \
    if ((T) <= 14) __builtin_amdgcn_s_barrier();                                             \
    __builtin_amdgcn_sched_barrier(0);                                                       \
} while (0)

    // prologue: tiles 0 and 1 in flight; wait tile 0 (6 newest = tile 1 fly on)
    STG_A(sA0, 0); STG_B2(sB0, 0, 0); STG_B2(sB0, 0, 2);
    STG_A(sA1, 1); STG_B2(sB1, 1, 0); STG_B2(sB1, 1, 2);
    __builtin_amdgcn_sched_barrier(0);
    asm volatile("s_waitcnt vmcnt(6)" ::: "memory");
    __builtin_amdgcn_s_barrier();
    __builtin_amdgcn_sched_barrier(0);

    BODY(sA0, sB0, sA2, sB2, 0);
    BODY(sA1, sB1, sA0, sB0, 1);
    BODY(sA2, sB2, sA1, sB1, 2);
    BODY(sA0, sB0, sA2, sB2, 3);
    BODY(sA1, sB1, sA0, sB0, 4);
    BODY(sA2, sB2, sA1, sB1, 5);
    BODY(sA0, sB0, sA2, sB2, 6);
    BODY(sA1, sB1, sA0, sB0, 7);
    BODY(sA2, sB2, sA1, sB1, 8);
    BODY(sA0, sB0, sA2, sB2, 9);
    BODY(sA1, sB1, sA0, sB0, 10);
    BODY(sA2, sB2, sA1, sB1, 11);
    BODY(sA0, sB0, sA2, sB2, 12);
    BODY(sA1, sB1, sA0, sB0, 13);
    BODY(sA2, sB2, sA1, sB1, 14);
    BODY(sA0, sB0, sA2, sB2, 15);

#undef BODY
#undef MFMA16
#undef RD_FRAGS
#undef STG_A
#undef STG_B2

    // epilogue: bias-select + tanh + bf16 store + partial logits
    // (all VMEM here is AFTER the loop; in-loop vmcnt counting stays exact)
    float u0v[4], u1v[4], wl0[4], wl1[4];
    int colg[4];
    #pragma unroll
    for (int n = 0; n < 4; ++n) {
        int c = colN + wc * 64 + n * 16 + fr;
        colg[n] = c;
        u0v[n] = u0[c]; u1v[n] = u1[c];
        wl0[n] = Wlin[c]; wl1[n] = Wlin[HID + c];
    }
    const int slot = blockIdx.y * 4 + wc;   // 16 slots

    #pragma unroll
    for (int m = 0; m < 4; ++m) {
        #pragma unroll
        for (int r = 0; r < 4; ++r) {
            long rowg = rowM + wr * 64 + m * 16 + fq * 4 + r;
            int bt = bits_s[rowg];
            float s0 = 0.f, s1 = 0.f;
            #pragma unroll
            for (int n = 0; n < 4; ++n) {
                float z  = acc[m][n][r] + (bt ? u1v[n] : u0v[n]);
                float hv = tanh_fast(z);
                hout[rowg * HID + colg[n]] = (bf16)hv;
                s0 += hv * wl0[n];
                s1 += hv * wl1[n];
            }
            #pragma unroll
            for (int off = 1; off < 16; off <<= 1) {
                s0 += __shfl_xor(s0, off, 16);
                s1 += __shfl_xor(s1, off, 16);
            }
            if (fr == 0)
                *(float2*)&plog_s[rowg * 32 + slot * 2] = make_float2(s0, s1);
        }
    }
}

// ---------------- finalize: softmax + permutation weights ----------------

__global__ void finalize(const float* __restrict__ plog, const float* __restrict__ l0s,
                         const float* __restrict__ blin, const unsigned int* __restrict__ words,
                         const float* __restrict__ fact, float* __restrict__ out) {
    long idx = (long)blockIdx.x * blockDim.x + threadIdx.x;
    if (idx >= (long)NSPIN * BATCH) return;
    int s = (int)(idx / BATCH), b = (int)(idx % BATCH);

    float l0, l1;
    if (s == 0) { l0 = l0s[0]; l1 = l0s[1]; }
    else {
        l0 = blin[0]; l1 = blin[1];
        const float* ps = plog + ((long)(s - 1) * BATCH + b) * 32;
        #pragma unroll
        for (int k = 0; k < 16; ++k) {
            l0 += ps[k * 2 + 0];
            l1 += ps[k * 2 + 1];
        }
    }
    float mx = fmaxf(l0, l1);
    float e0 = __expf(l0 - mx), e1 = __expf(l1 - mx);
    float p0 = e0 / (e0 + e1), p1 = e1 / (e0 + e1);
    if (s > 0) {
        const unsigned int wv = words[b];
        const int cd = __popc(wv & ((1u << s) - 1));
        const float cdf = (float)cd, cuf = (float)(s - cd);
        const float ku = 16.f - cuf, kd = 16.f - cdf;
        const int n = NSPIN - s;
        const int kui = (int)fminf(fmaxf(ku, 0.f), 32.f);
        const int kdi = (int)fminf(fmaxf(kd, 0.f), 32.f);
        const float wu = fact[n] / fact[kui] * (ku >= 0.f ? 1.f : 0.f) + 1e-12f;
        const float wd = fact[n] / fact[kdi] * (kd >= 0.f ? 1.f : 0.f) + 1e-12f;
        p0 *= wu; p1 *= wd;
    }
    float inv = 1.f / (p0 + p1);
    out[idx * 2 + 0] = p0 * inv;
    out[idx * 2 + 1] = p1 * inv;
}

// ---------------- launch ----------------

extern "C" void kernel_launch(void* const* d_in, const int* in_sizes, int n_in,
                              void* d_out, int out_size, void* d_ws, size_t ws_size,
                              hipStream_t stream) {
    const float* din  = (const float*)d_in[0];  // [32][8192][2]
    const float* Wih  = (const float*)d_in[1];  // [1024][2]
    const float* Whh  = (const float*)d_in[2];  // [1024][1024]
    const float* bih  = (const float*)d_in[3];  // [1024]
    const float* bhh  = (const float*)d_in[4];  // [1024]
    const float* Wlin = (const float*)d_in[5];  // [2][1024]
    const float* blin = (const float*)d_in[6];  // [2]
    float* out = (float*)d_out;

    char* ws = (char*)d_ws;
    size_t o = 0;
    auto alloc = [&](size_t b) { size_t r = o; o += (b + 255) & ~(size_t)255; return r; };
    bf16*  Wbf  = (bf16*)(ws + alloc((size_t)HID * HID * 2));
    float* u0   = (float*)(ws + alloc(HID * 4));
    float* u1   = (float*)(ws + alloc(HID * 4));
    bf16*  hrow = (bf16*)(ws + alloc(HID * 2));
    float* l0s  = (float*)(ws + alloc(2 * 4));
    float* fact = (float*)(ws + alloc(33 * 4));
    unsigned char* bits = (unsigned char*)(ws + alloc(31L * BATCH));
    unsigned int* words = (unsigned int*)(ws + alloc((size_t)BATCH * 4));
    bf16*  hA   = (bf16*)(ws + alloc((size_t)BATCH * HID * 2));
    bf16*  hB   = (bf16*)(ws + alloc((size_t)BATCH * HID * 2));
    float* plog = (float*)(ws + alloc(31L * BATCH * 16 * 2 * 4));

    prep1<<<1024, 256, 0, stream>>>(din, Wih, Whh, bih, bhh, Wbf, u0, u1, bits, words, fact);
    prep2<<<1, 1024, 0, stream>>>(u0, Wlin, blin, hrow, l0s);
    fillh<<<2048, 256, 0, stream>>>(hrow, hA);

    bf16* hin = hA; bf16* hout = hB;
    for (int s = 1; s <= 31; ++s) {
        gemm_step<<<dim3(64, 4), 512, 0, stream>>>(
            hin, hout, Wbf, u0, u1,
            bits + (size_t)(s - 1) * BATCH, Wlin,
            plog + (size_t)(s - 1) * BATCH * 32);
        bf16* t = hin; hin = hout; hout = t;
    }
    finalize<<<(NSPIN * BATCH) / 256, 256, 0, stream>>>(plog, l0s, blin, words, fact, out);
}